// Round 14
// baseline (119.915 us; speedup 1.0000x reference)
//
#include <hip/hip_runtime.h>
#include <hip/hip_bf16.h>
#include <math.h>

// Problem constants
#define BB 4
#define CC 64
#define HH 128
#define WW 128
#define HW 16384
#define CHW (CC*HW)

typedef __bf16 bf16;
typedef __attribute__((ext_vector_type(8))) __bf16 bf16x8;
typedef __attribute__((ext_vector_type(4))) __bf16 bf16x4;
typedef __attribute__((ext_vector_type(4))) float f32x4;
typedef __attribute__((ext_vector_type(4))) unsigned short u16x4;

#define MFMA(a, b, c) __builtin_amdgcn_mfma_f32_16x16x32_bf16((a), (b), (c), 0, 0, 0)

// ---- Pre-kernel: x NCHW -> NHWC bf16 (blocks 0..511, 64ch x 128sp tiles)
//      + weight frags (blocks 512..727)
__global__ __launch_bounds__(256) void k_pre(const float* __restrict__ x,
        bf16* __restrict__ xt,
        const float* __restrict__ dw, const float* __restrict__ ow,
        const float* __restrict__ mw,
        bf16* __restrict__ wfd_hi, bf16* __restrict__ wfd_lo,
        bf16* __restrict__ wfo_hi, bf16* __restrict__ wfo_lo) {
    __shared__ float tile[64][129];
    if (blockIdx.x < 512) {
        int b    = blockIdx.x >> 7;                 // 128 tiles per batch
        int s0   = (blockIdx.x & 127) * 128;
        int t    = threadIdx.x;
        const float* xb = x + (size_t)b * CHW;
        // reads: 2048 tasks = 64 ch-rows x 32 col4-chunks (512B/row contiguous)
        #pragma unroll
        for (int it = 0; it < 8; ++it) {
            int task = it * 256 + t;
            int c    = task >> 5;
            int col4 = (task & 31) * 4;
            float4 v = *(const float4*)&xb[(size_t)c * HW + s0 + col4];
            tile[c][col4 + 0] = v.x;
            tile[c][col4 + 1] = v.y;
            tile[c][col4 + 2] = v.z;
            tile[c][col4 + 3] = v.w;
        }
        __syncthreads();
        bf16* xtb = xt + (size_t)b * CHW;
        // stores: 1024 tasks = 128 s x 8 ch-chunks -> 16B stores, contiguous
        #pragma unroll
        for (int it = 0; it < 4; ++it) {
            int task = it * 256 + t;
            int s = task >> 3, ch0 = (task & 7) * 8;
            bf16x8 v;
            #pragma unroll
            for (int j = 0; j < 8; ++j) v[j] = (bf16)tile[ch0 + j][s];
            *(bf16x8*)&xtb[(size_t)(s0 + s) * 64 + ch0] = v;
        }
    } else {
        int idx = (blockIdx.x - 512) * 256 + threadIdx.x;
        if (idx < 36864) {                          // deform frags: 4 nt * 18 ks * 64 lanes * 8
            int j    = idx & 7;
            int lane = (idx >> 3) & 63;
            int ks   = (idx >> 9) % 18;
            int nt   = idx / (512 * 18);
            int n    = nt * 16 + (lane & 15);
            int kglob = ks * 32 + (lane >> 4) * 8 + j;
            int kk = kglob >> 6, c = kglob & 63;    // K-order: k = kk*64 + c
            float w = dw[(n * 64 + c) * 9 + kk];
            bf16 h = (bf16)w;
            wfd_hi[idx] = h;
            wfd_lo[idx] = (bf16)(w - (float)h);
        } else {
            int idx2 = idx - 36864;                 // offmask frags: 2 nt
            int j    = idx2 & 7;
            int lane = (idx2 >> 3) & 63;
            int ks   = (idx2 >> 9) % 18;
            int nt   = idx2 / (512 * 18);
            int ch   = nt * 16 + (lane & 15);
            int kglob = ks * 32 + (lane >> 4) * 8 + j;
            int kk = kglob >> 6, c = kglob & 63;
            float w = 0.0f;
            if (ch < 18)      w = ow[(ch * 64 + c) * 9 + kk];
            else if (ch < 27) w = mw[((ch - 18) * 64 + c) * 9 + kk];
            bf16 h = (bf16)w;
            wfo_hi[idx2] = h;
            wfo_lo[idx2] = (bf16)(w - (float)h);
        }
    }
}

// ---- Fused kernel: R11 (best, 119.2) + MERGED-D (isolated retest of R8's
//      merged dual-chain D, now free of the C2 scratch-spill confound)
__global__ __launch_bounds__(256) void k_fused(const bf16* __restrict__ xt,
        const bf16* __restrict__ wfo_hi, const bf16* __restrict__ wfo_lo,
        const bf16* __restrict__ wfd_hi,
        const float* __restrict__ ob, const float* __restrict__ mb,
        const float* __restrict__ db, float* __restrict__ out) {
    __shared__ __align__(16) bf16 a_s2[2][18 * 64 * 8];    // 36864 B (st-pair)
    __shared__ float om_s[27 * 65];                        // 7020 B (stride 65)
    __shared__ __align__(8) bf16 sampw[576 * 4];           // 4608 B
    __shared__ __align__(8) unsigned short sampo[576 * 4]; // 4608 B

    // XCD-chunked swizzle (1024 blocks, 8 XCDs, bijective)
    int bid = (blockIdx.x & 7) * 128 + (blockIdx.x >> 3);
    int pos0 = bid * 64;
    int wo0 = pos0 & 127;
    int ho  = (pos0 >> 7) & 127;
    int b   = pos0 >> 14;
    int t = threadIdx.x, wave = t >> 6, lane = t & 63;
    int m = lane & 15, g = lane >> 4;
    const bf16* xtb = xt + (size_t)b * CHW;

    // ---- Phase B: offset/mask GEMM, wave = st, A-frags direct from global ----
    {
        int st = wave;
        f32x4 acc0 = {0.f, 0.f, 0.f, 0.f};
        f32x4 acc1 = {0.f, 0.f, 0.f, 0.f};
        const bf16x8* bh0 = (const bf16x8*)wfo_hi + lane;
        const bf16x8* bl0 = (const bf16x8*)wfo_lo + lane;
        const bf16x8* bh1 = (const bf16x8*)wfo_hi + 18 * 64 + lane;
        const bf16x8* bl1 = (const bf16x8*)wfo_lo + 18 * 64 + lane;
        #pragma unroll
        for (int kk = 0; kk < 9; ++kk) {
            int y  = ho + kk / 3 - 1;
            int xx = wo0 + st * 16 + m + (kk % 3) - 1;
            bf16x8 ae = {};
            bf16x8 ao = {};
            if ((unsigned)y < 128u && (unsigned)xx < 128u) {
                const bf16* bp = xtb + ((size_t)(y * 128 + xx) << 6);
                ae = *(const bf16x8*)(bp + g * 8);
                ao = *(const bf16x8*)(bp + 32 + g * 8);
            }
            int ks0 = 2 * kk, ks1 = 2 * kk + 1;
            acc0 = MFMA(ae, bh0[ks0 * 64], acc0);
            acc0 = MFMA(ae, bl0[ks0 * 64], acc0);
            acc0 = MFMA(ao, bh0[ks1 * 64], acc0);
            acc0 = MFMA(ao, bl0[ks1 * 64], acc0);
            acc1 = MFMA(ae, bh1[ks0 * 64], acc1);
            acc1 = MFMA(ae, bl1[ks0 * 64], acc1);
            acc1 = MFMA(ao, bh1[ks1 * 64], acc1);
            acc1 = MFMA(ao, bl1[ks1 * 64], acc1);
        }
        int p64 = st * 16 + g * 4;
        float bias0 = ob[m];                        // ch = m, always < 18
        #pragma unroll
        for (int r = 0; r < 4; ++r)
            om_s[m * 65 + p64 + r] = acc0[r] + bias0;
        int ch1 = 16 + m;
        if (ch1 < 27) {
            float bias1 = (ch1 < 18) ? ob[ch1] : mb[ch1 - 18];
            #pragma unroll
            for (int r = 0; r < 4; ++r) {
                float v = acc1[r] + bias1;
                if (ch1 >= 18) v = 1.0f / (1.0f + __expf(-v));
                om_s[ch1 * 65 + p64 + r] = v;
            }
        }
    }
    __syncthreads();

    // ---- Phase C1: bilinear scalar precompute (576 tasks) ----
    for (int task = t; task < 576; task += 256) {
        int p64 = task / 9, k = task - p64 * 9;
        float dy = om_s[(2 * k) * 65 + p64];
        float dx = om_s[(2 * k + 1) * 65 + p64];
        float mk = om_s[(18 + k) * 65 + p64];
        float py = (float)(ho - 1 + k / 3) + dy;
        float px = (float)(wo0 + p64 - 1 + (k % 3)) + dx;
        float y0f = floorf(py), x0f = floorf(px);
        float fy = py - y0f, fx = px - x0f;
        int y0 = (int)y0f, x0 = (int)x0f;
        int y1 = y0 + 1,  x1 = x0 + 1;
        bool vy0 = (unsigned)y0 < 128u, vy1 = (unsigned)y1 < 128u;
        bool vx0 = (unsigned)x0 < 128u, vx1 = (unsigned)x1 < 128u;
        int y0c = min(max(y0, 0), 127), y1c = min(max(y1, 0), 127);
        int x0c = min(max(x0, 0), 127), x1c = min(max(x1, 0), 127);
        bf16x4 wv;
        wv.x = (bf16)((vy0 && vx0) ? mk * (1.f - fy) * (1.f - fx) : 0.f);
        wv.y = (bf16)((vy0 && vx1) ? mk * (1.f - fy) * fx         : 0.f);
        wv.z = (bf16)((vy1 && vx0) ? mk * fy * (1.f - fx)         : 0.f);
        wv.w = (bf16)((vy1 && vx1) ? mk * fy * fx                 : 0.f);
        u16x4 ov;
        ov.x = (unsigned short)(y0c * 128 + x0c);
        ov.y = (unsigned short)(y0c * 128 + x1c);
        ov.z = (unsigned short)(y1c * 128 + x0c);
        ov.w = (unsigned short)(y1c * 128 + x1c);
        *(bf16x4*)&sampw[task * 4] = wv;
        *(u16x4*)&sampo[task * 4] = ov;
    }
    __syncthreads();

    // ---- st-pair loop: pipelined C2 (static regs) -> MERGED D GEMM ----
    const bf16x8* bhd = (const bf16x8*)wfd_hi + (size_t)wave * 18 * 64 + lane;
    int fle = ((m ^ g) + (g << 4)) * 8;             // D-read offsets (elements)
    int flo = ((m ^ g ^ 4) + (g << 4)) * 8;
    // C2 thread mapping: half selects st within pair; prow = row in st;
    // c8 = 8-channel chunk. ks parity = kpar is loop-invariant.
    int half = t >> 7;
    int prow = (t >> 3) & 15;
    int c8   = (t & 7) * 8;
    int kpar = c8 >> 5;
    int gch  = (c8 & 31) >> 3;
    int flw  = (prow ^ gch ^ (kpar << 2)) + (gch << 4);   // write slot (16B units)
    char* abw = (char*)&a_s2[half][0] + (flw << 4);

// 2-stage software pipeline, all-static names (rule-#20 safe)
#define LDS_(W, O, KK) { \
        W = *(const bf16x4*)&sampw[(taskbase + (KK)) * 4]; \
        O = *(const u16x4*)&sampo[(taskbase + (KK)) * 4]; }
#define COR_(C0, C1, C2v, C3, O) { \
        C0  = *(const bf16x8*)&xtb[((int)(O).x << 6) + c8]; \
        C1  = *(const bf16x8*)&xtb[((int)(O).y << 6) + c8]; \
        C2v = *(const bf16x8*)&xtb[((int)(O).z << 6) + c8]; \
        C3  = *(const bf16x8*)&xtb[((int)(O).w << 6) + c8]; }
#define PCK_(W, C0, C1, C2v, C3, KK) { \
        float w00 = (float)(W).x, w01 = (float)(W).y; \
        float w10 = (float)(W).z, w11 = (float)(W).w; \
        bf16x8 hv; \
        _Pragma("unroll") \
        for (int j = 0; j < 8; ++j) { \
            float r = w00 * (float)(C0)[j] + w01 * (float)(C1)[j] \
                    + w10 * (float)(C2v)[j] + w11 * (float)(C3)[j]; \
            hv[j] = (bf16)r; } \
        *(bf16x8*)(abw + ((2 * (KK) + kpar) << 10)) = hv; }

    #pragma unroll
    for (int sp = 0; sp < 2; ++sp) {
        // C2: gather rows of sts {2sp, 2sp+1} into a_s2[0]/a_s2[1]
        {
            int stc = sp * 2 + half;
            int taskbase = (stc * 16 + prow) * 9;
            bf16x4 wA, wB; u16x4 oA, oB;
            bf16x8 A0, A1, A2, A3, B0, B1, B2, B3;
            LDS_(wA, oA, 0); COR_(A0, A1, A2, A3, oA);
            LDS_(wB, oB, 1); COR_(B0, B1, B2, B3, oB);
            PCK_(wA, A0, A1, A2, A3, 0);
            LDS_(wA, oA, 2); COR_(A0, A1, A2, A3, oA);
            PCK_(wB, B0, B1, B2, B3, 1);
            LDS_(wB, oB, 3); COR_(B0, B1, B2, B3, oB);
            PCK_(wA, A0, A1, A2, A3, 2);
            LDS_(wA, oA, 4); COR_(A0, A1, A2, A3, oA);
            PCK_(wB, B0, B1, B2, B3, 3);
            LDS_(wB, oB, 5); COR_(B0, B1, B2, B3, oB);
            PCK_(wA, A0, A1, A2, A3, 4);
            LDS_(wA, oA, 6); COR_(A0, A1, A2, A3, oA);
            PCK_(wB, B0, B1, B2, B3, 5);
            LDS_(wB, oB, 7); COR_(B0, B1, B2, B3, oB);
            PCK_(wA, A0, A1, A2, A3, 6);
            LDS_(wA, oA, 8); COR_(A0, A1, A2, A3, oA);
            PCK_(wB, B0, B1, B2, B3, 7);
            PCK_(wA, A0, A1, A2, A3, 8);
        }
        __syncthreads();

        // ---- D: MERGED deform GEMM for both half-sts, wave = o-tile ----
        // Shared B-operand loads (36 -> 18 per pair), two independent
        // 18-deep MFMA chains interleaved in the matrix pipe.
        {
            f32x4 acc0 = {0.f, 0.f, 0.f, 0.f};
            f32x4 acc1 = {0.f, 0.f, 0.f, 0.f};
            __builtin_amdgcn_s_setprio(1);
            #pragma unroll
            for (int kk = 0; kk < 9; ++kk) {
                bf16x8 b0 = bhd[(2 * kk) * 64];
                bf16x8 b1 = bhd[(2 * kk + 1) * 64];
                bf16x8 a0e = *(const bf16x8*)&a_s2[0][(2 * kk) * 512 + fle];
                bf16x8 a0o = *(const bf16x8*)&a_s2[0][(2 * kk + 1) * 512 + flo];
                bf16x8 a1e = *(const bf16x8*)&a_s2[1][(2 * kk) * 512 + fle];
                bf16x8 a1o = *(const bf16x8*)&a_s2[1][(2 * kk + 1) * 512 + flo];
                acc0 = MFMA(a0e, b0, acc0);
                acc1 = MFMA(a1e, b0, acc1);
                acc0 = MFMA(a0o, b1, acc0);
                acc1 = MFMA(a1o, b1, acc1);
            }
            __builtin_amdgcn_s_setprio(0);
            int o = wave * 16 + m;
            float bias = db[o];
            int st0 = sp * 2;
            float4 v0 = {acc0[0] + bias, acc0[1] + bias, acc0[2] + bias, acc0[3] + bias};
            float4 v1 = {acc1[0] + bias, acc1[1] + bias, acc1[2] + bias, acc1[3] + bias};
            size_t obase = ((size_t)(b * 64 + o)) * HW + ho * 128 + wo0 + g * 4;
            *(float4*)&out[obase + st0 * 16] = v0;
            *(float4*)&out[obase + (st0 + 1) * 16] = v1;
        }
        if (sp == 0) __syncthreads();
    }
#undef LDS_
#undef COR_
#undef PCK_
}

extern "C" void kernel_launch(void* const* d_in, const int* in_sizes, int n_in,
                              void* d_out, int out_size, void* d_ws, size_t ws_size,
                              hipStream_t stream) {
    const float* x   = (const float*)d_in[0];
    const float* ow  = (const float*)d_in[1];
    const float* ob  = (const float*)d_in[2];
    const float* mw  = (const float*)d_in[3];
    const float* mb  = (const float*)d_in[4];
    const float* dw  = (const float*)d_in[5];
    const float* db  = (const float*)d_in[6];
    float* out = (float*)d_out;

    bf16* xt = (bf16*)d_ws;                         // 4,194,304 bf16 = 8 MB
    bf16* wfd_hi = xt + (size_t)BB * HW * CC;
    bf16* wfd_lo = wfd_hi + 36864;
    bf16* wfo_hi = wfd_lo + 36864;
    bf16* wfo_lo = wfo_hi + 18432;

    k_pre<<<512 + 216, 256, 0, stream>>>(x, xt, dw, ow, mw, wfd_hi, wfd_lo, wfo_hi, wfo_lo);
    k_fused<<<(BB * HW) / 64, 256, 0, stream>>>(xt, wfo_hi, wfo_lo, wfd_hi, ob, mb, db, out);
}

// Round 15
// 118.734 us; speedup vs baseline: 1.0099x; 1.0099x over previous
//
#include <hip/hip_runtime.h>
#include <hip/hip_bf16.h>
#include <math.h>

// Problem constants
#define BB 4
#define CC 64
#define HH 128
#define WW 128
#define HW 16384
#define CHW (CC*HW)

typedef __bf16 bf16;
typedef __attribute__((ext_vector_type(8))) __bf16 bf16x8;
typedef __attribute__((ext_vector_type(4))) __bf16 bf16x4;
typedef __attribute__((ext_vector_type(4))) float f32x4;
typedef __attribute__((ext_vector_type(4))) unsigned short u16x4;

#define MFMA(a, b, c) __builtin_amdgcn_mfma_f32_16x16x32_bf16((a), (b), (c), 0, 0, 0)

// ---- Pre-kernel: x NCHW -> NHWC bf16 (blocks 0..511, 64ch x 128sp tiles)
//      + weight frags (blocks 512..727)
__global__ __launch_bounds__(256) void k_pre(const float* __restrict__ x,
        bf16* __restrict__ xt,
        const float* __restrict__ dw, const float* __restrict__ ow,
        const float* __restrict__ mw,
        bf16* __restrict__ wfd_hi, bf16* __restrict__ wfd_lo,
        bf16* __restrict__ wfo_hi, bf16* __restrict__ wfo_lo) {
    __shared__ float tile[64][129];
    if (blockIdx.x < 512) {
        int b    = blockIdx.x >> 7;                 // 128 tiles per batch
        int s0   = (blockIdx.x & 127) * 128;
        int t    = threadIdx.x;
        const float* xb = x + (size_t)b * CHW;
        // reads: 2048 tasks = 64 ch-rows x 32 col4-chunks (512B/row contiguous)
        #pragma unroll
        for (int it = 0; it < 8; ++it) {
            int task = it * 256 + t;
            int c    = task >> 5;
            int col4 = (task & 31) * 4;
            float4 v = *(const float4*)&xb[(size_t)c * HW + s0 + col4];
            tile[c][col4 + 0] = v.x;
            tile[c][col4 + 1] = v.y;
            tile[c][col4 + 2] = v.z;
            tile[c][col4 + 3] = v.w;
        }
        __syncthreads();
        bf16* xtb = xt + (size_t)b * CHW;
        // stores: 1024 tasks = 128 s x 8 ch-chunks -> 16B stores, contiguous
        #pragma unroll
        for (int it = 0; it < 4; ++it) {
            int task = it * 256 + t;
            int s = task >> 3, ch0 = (task & 7) * 8;
            bf16x8 v;
            #pragma unroll
            for (int j = 0; j < 8; ++j) v[j] = (bf16)tile[ch0 + j][s];
            *(bf16x8*)&xtb[(size_t)(s0 + s) * 64 + ch0] = v;
        }
    } else {
        int idx = (blockIdx.x - 512) * 256 + threadIdx.x;
        if (idx < 36864) {                          // deform frags: 4 nt * 18 ks * 64 lanes * 8
            int j    = idx & 7;
            int lane = (idx >> 3) & 63;
            int ks   = (idx >> 9) % 18;
            int nt   = idx / (512 * 18);
            int n    = nt * 16 + (lane & 15);
            int kglob = ks * 32 + (lane >> 4) * 8 + j;
            int kk = kglob >> 6, c = kglob & 63;    // K-order: k = kk*64 + c
            float w = dw[(n * 64 + c) * 9 + kk];
            bf16 h = (bf16)w;
            wfd_hi[idx] = h;
            wfd_lo[idx] = (bf16)(w - (float)h);
        } else {
            int idx2 = idx - 36864;                 // offmask frags: 2 nt
            int j    = idx2 & 7;
            int lane = (idx2 >> 3) & 63;
            int ks   = (idx2 >> 9) % 18;
            int nt   = idx2 / (512 * 18);
            int ch   = nt * 16 + (lane & 15);
            int kglob = ks * 32 + (lane >> 4) * 8 + j;
            int kk = kglob >> 6, c = kglob & 63;
            float w = 0.0f;
            if (ch < 18)      w = ow[(ch * 64 + c) * 9 + kk];
            else if (ch < 27) w = mw[((ch - 18) * 64 + c) * 9 + kk];
            bf16 h = (bf16)w;
            wfo_hi[idx2] = h;
            wfo_lo[idx2] = (bf16)(w - (float)h);
        }
    }
}

// ---- Fused kernel: R11 (best, 119.2) with WAVE-LOCAL C1 ----
// Phase B's wave st produces all 27 channels of its own 16 positions, so C1
// for those positions is wave-internal: the B->C1 block barrier is replaced
// by s_waitcnt lgkmcnt(0), and each wave starts C1 as soon as ITS B is done.
// Task values are bitwise identical (same arithmetic, different thread map).
__global__ __launch_bounds__(256) void k_fused(const bf16* __restrict__ xt,
        const bf16* __restrict__ wfo_hi, const bf16* __restrict__ wfo_lo,
        const bf16* __restrict__ wfd_hi,
        const float* __restrict__ ob, const float* __restrict__ mb,
        const float* __restrict__ db, float* __restrict__ out) {
    __shared__ __align__(16) bf16 a_s2[2][18 * 64 * 8];    // 36864 B (st-pair)
    __shared__ float om_s[27 * 65];                        // 7020 B (stride 65)
    __shared__ __align__(8) bf16 sampw[576 * 4];           // 4608 B
    __shared__ __align__(8) unsigned short sampo[576 * 4]; // 4608 B

    // XCD-chunked swizzle (1024 blocks, 8 XCDs, bijective)
    int bid = (blockIdx.x & 7) * 128 + (blockIdx.x >> 3);
    int pos0 = bid * 64;
    int wo0 = pos0 & 127;
    int ho  = (pos0 >> 7) & 127;
    int b   = pos0 >> 14;
    int t = threadIdx.x, wave = t >> 6, lane = t & 63;
    int m = lane & 15, g = lane >> 4;
    const bf16* xtb = xt + (size_t)b * CHW;

    // ---- Phase B: offset/mask GEMM, wave = st, A-frags direct from global ----
    {
        int st = wave;
        f32x4 acc0 = {0.f, 0.f, 0.f, 0.f};
        f32x4 acc1 = {0.f, 0.f, 0.f, 0.f};
        const bf16x8* bh0 = (const bf16x8*)wfo_hi + lane;
        const bf16x8* bl0 = (const bf16x8*)wfo_lo + lane;
        const bf16x8* bh1 = (const bf16x8*)wfo_hi + 18 * 64 + lane;
        const bf16x8* bl1 = (const bf16x8*)wfo_lo + 18 * 64 + lane;
        #pragma unroll
        for (int kk = 0; kk < 9; ++kk) {
            int y  = ho + kk / 3 - 1;
            int xx = wo0 + st * 16 + m + (kk % 3) - 1;
            bf16x8 ae = {};
            bf16x8 ao = {};
            if ((unsigned)y < 128u && (unsigned)xx < 128u) {
                const bf16* bp = xtb + ((size_t)(y * 128 + xx) << 6);
                ae = *(const bf16x8*)(bp + g * 8);
                ao = *(const bf16x8*)(bp + 32 + g * 8);
            }
            int ks0 = 2 * kk, ks1 = 2 * kk + 1;
            acc0 = MFMA(ae, bh0[ks0 * 64], acc0);
            acc0 = MFMA(ae, bl0[ks0 * 64], acc0);
            acc0 = MFMA(ao, bh0[ks1 * 64], acc0);
            acc0 = MFMA(ao, bl0[ks1 * 64], acc0);
            acc1 = MFMA(ae, bh1[ks0 * 64], acc1);
            acc1 = MFMA(ae, bl1[ks0 * 64], acc1);
            acc1 = MFMA(ao, bh1[ks1 * 64], acc1);
            acc1 = MFMA(ao, bl1[ks1 * 64], acc1);
        }
        int p64 = st * 16 + g * 4;
        float bias0 = ob[m];                        // ch = m, always < 18
        #pragma unroll
        for (int r = 0; r < 4; ++r)
            om_s[m * 65 + p64 + r] = acc0[r] + bias0;
        int ch1 = 16 + m;
        if (ch1 < 27) {
            float bias1 = (ch1 < 18) ? ob[ch1] : mb[ch1 - 18];
            #pragma unroll
            for (int r = 0; r < 4; ++r) {
                float v = acc1[r] + bias1;
                if (ch1 >= 18) v = 1.0f / (1.0f + __expf(-v));
                om_s[ch1 * 65 + p64 + r] = v;
            }
        }
    }
    // wave-local ordering only: this wave's C1 reads only this wave's om_s rows
    asm volatile("s_waitcnt lgkmcnt(0)" ::: "memory");

    // ---- Phase C1: bilinear scalars, WAVE-LOCAL (wave st: its 144 tasks) ----
    {
        int tb144 = wave * 144;                     // tasks [st*144, st*144+144)
        for (int i = lane; i < 144; i += 64) {
            int task = tb144 + i;
            int p64 = task / 9, k = task - p64 * 9;
            float dy = om_s[(2 * k) * 65 + p64];
            float dx = om_s[(2 * k + 1) * 65 + p64];
            float mk = om_s[(18 + k) * 65 + p64];
            float py = (float)(ho - 1 + k / 3) + dy;
            float px = (float)(wo0 + p64 - 1 + (k % 3)) + dx;
            float y0f = floorf(py), x0f = floorf(px);
            float fy = py - y0f, fx = px - x0f;
            int y0 = (int)y0f, x0 = (int)x0f;
            int y1 = y0 + 1,  x1 = x0 + 1;
            bool vy0 = (unsigned)y0 < 128u, vy1 = (unsigned)y1 < 128u;
            bool vx0 = (unsigned)x0 < 128u, vx1 = (unsigned)x1 < 128u;
            int y0c = min(max(y0, 0), 127), y1c = min(max(y1, 0), 127);
            int x0c = min(max(x0, 0), 127), x1c = min(max(x1, 0), 127);
            bf16x4 wv;
            wv.x = (bf16)((vy0 && vx0) ? mk * (1.f - fy) * (1.f - fx) : 0.f);
            wv.y = (bf16)((vy0 && vx1) ? mk * (1.f - fy) * fx         : 0.f);
            wv.z = (bf16)((vy1 && vx0) ? mk * fy * (1.f - fx)         : 0.f);
            wv.w = (bf16)((vy1 && vx1) ? mk * fy * fx                 : 0.f);
            u16x4 ov;
            ov.x = (unsigned short)(y0c * 128 + x0c);
            ov.y = (unsigned short)(y0c * 128 + x1c);
            ov.z = (unsigned short)(y1c * 128 + x0c);
            ov.w = (unsigned short)(y1c * 128 + x1c);
            *(bf16x4*)&sampw[task * 4] = wv;
            *(u16x4*)&sampo[task * 4] = ov;
        }
    }
    __syncthreads();                                // samp visible to all waves

    // ---- st-pair loop: pipelined C2 (static regs) -> D GEMM x2 ----
    const bf16x8* bhd = (const bf16x8*)wfd_hi + (size_t)wave * 18 * 64 + lane;
    int fle = ((m ^ g) + (g << 4)) * 8;             // D-read offsets (elements)
    int flo = ((m ^ g ^ 4) + (g << 4)) * 8;
    // C2 thread mapping: half selects st within pair; prow = row in st;
    // c8 = 8-channel chunk. ks parity = kpar is loop-invariant.
    int half = t >> 7;
    int prow = (t >> 3) & 15;
    int c8   = (t & 7) * 8;
    int kpar = c8 >> 5;
    int gch  = (c8 & 31) >> 3;
    int flw  = (prow ^ gch ^ (kpar << 2)) + (gch << 4);   // write slot (16B units)
    char* abw = (char*)&a_s2[half][0] + (flw << 4);

// 2-stage software pipeline, all-static names (rule-#20 safe)
#define LDS_(W, O, KK) { \
        W = *(const bf16x4*)&sampw[(taskbase + (KK)) * 4]; \
        O = *(const u16x4*)&sampo[(taskbase + (KK)) * 4]; }
#define COR_(C0, C1, C2v, C3, O) { \
        C0  = *(const bf16x8*)&xtb[((int)(O).x << 6) + c8]; \
        C1  = *(const bf16x8*)&xtb[((int)(O).y << 6) + c8]; \
        C2v = *(const bf16x8*)&xtb[((int)(O).z << 6) + c8]; \
        C3  = *(const bf16x8*)&xtb[((int)(O).w << 6) + c8]; }
#define PCK_(W, C0, C1, C2v, C3, KK) { \
        float w00 = (float)(W).x, w01 = (float)(W).y; \
        float w10 = (float)(W).z, w11 = (float)(W).w; \
        bf16x8 hv; \
        _Pragma("unroll") \
        for (int j = 0; j < 8; ++j) { \
            float r = w00 * (float)(C0)[j] + w01 * (float)(C1)[j] \
                    + w10 * (float)(C2v)[j] + w11 * (float)(C3)[j]; \
            hv[j] = (bf16)r; } \
        *(bf16x8*)(abw + ((2 * (KK) + kpar) << 10)) = hv; }

    #pragma unroll
    for (int sp = 0; sp < 2; ++sp) {
        // C2: gather rows of sts {2sp, 2sp+1} into a_s2[0]/a_s2[1]
        {
            int stc = sp * 2 + half;
            int taskbase = (stc * 16 + prow) * 9;
            bf16x4 wA, wB; u16x4 oA, oB;
            bf16x8 A0, A1, A2, A3, B0, B1, B2, B3;
            LDS_(wA, oA, 0); COR_(A0, A1, A2, A3, oA);
            LDS_(wB, oB, 1); COR_(B0, B1, B2, B3, oB);
            PCK_(wA, A0, A1, A2, A3, 0);
            LDS_(wA, oA, 2); COR_(A0, A1, A2, A3, oA);
            PCK_(wB, B0, B1, B2, B3, 1);
            LDS_(wB, oB, 3); COR_(B0, B1, B2, B3, oB);
            PCK_(wA, A0, A1, A2, A3, 2);
            LDS_(wA, oA, 4); COR_(A0, A1, A2, A3, oA);
            PCK_(wB, B0, B1, B2, B3, 3);
            LDS_(wB, oB, 5); COR_(B0, B1, B2, B3, oB);
            PCK_(wA, A0, A1, A2, A3, 4);
            LDS_(wA, oA, 6); COR_(A0, A1, A2, A3, oA);
            PCK_(wB, B0, B1, B2, B3, 5);
            LDS_(wB, oB, 7); COR_(B0, B1, B2, B3, oB);
            PCK_(wA, A0, A1, A2, A3, 6);
            LDS_(wA, oA, 8); COR_(A0, A1, A2, A3, oA);
            PCK_(wB, B0, B1, B2, B3, 7);
            PCK_(wA, A0, A1, A2, A3, 8);
        }
        __syncthreads();

        // D: deform GEMM for the two sts of this pair, wave = o-tile (as R11)
        #pragma unroll
        for (int h2 = 0; h2 < 2; ++h2) {
            int st = sp * 2 + h2;
            const bf16* ab = &a_s2[h2][0];
            f32x4 acc = {0.f, 0.f, 0.f, 0.f};
            __builtin_amdgcn_s_setprio(1);
            #pragma unroll
            for (int kk = 0; kk < 9; ++kk) {
                bf16x8 a0 = *(const bf16x8*)&ab[(2 * kk) * 512 + fle];
                bf16x8 a1 = *(const bf16x8*)&ab[(2 * kk + 1) * 512 + flo];
                acc = MFMA(a0, bhd[(2 * kk) * 64], acc);
                acc = MFMA(a1, bhd[(2 * kk + 1) * 64], acc);
            }
            __builtin_amdgcn_s_setprio(0);
            int o = wave * 16 + m;
            float bias = db[o];
            float4 vv = {acc[0] + bias, acc[1] + bias, acc[2] + bias, acc[3] + bias};
            *(float4*)&out[((size_t)(b * 64 + o)) * HW + ho * 128 + wo0 + st * 16 + g * 4] = vv;
        }
        if (sp == 0) __syncthreads();
    }
#undef LDS_
#undef COR_
#undef PCK_
}

extern "C" void kernel_launch(void* const* d_in, const int* in_sizes, int n_in,
                              void* d_out, int out_size, void* d_ws, size_t ws_size,
                              hipStream_t stream) {
    const float* x   = (const float*)d_in[0];
    const float* ow  = (const float*)d_in[1];
    const float* ob  = (const float*)d_in[2];
    const float* mw  = (const float*)d_in[3];
    const float* mb  = (const float*)d_in[4];
    const float* dw  = (const float*)d_in[5];
    const float* db  = (const float*)d_in[6];
    float* out = (float*)d_out;

    bf16* xt = (bf16*)d_ws;                         // 4,194,304 bf16 = 8 MB
    bf16* wfd_hi = xt + (size_t)BB * HW * CC;
    bf16* wfd_lo = wfd_hi + 36864;
    bf16* wfo_hi = wfd_lo + 36864;
    bf16* wfo_lo = wfo_hi + 18432;

    k_pre<<<512 + 216, 256, 0, stream>>>(x, xt, dw, ow, mw, wfd_hi, wfd_lo, wfo_hi, wfo_lo);
    k_fused<<<(BB * HW) / 64, 256, 0, stream>>>(xt, wfo_hi, wfo_lo, wfd_hi, ob, mb, db, out);
}